// Round 1
// 583.989 us; speedup vs baseline: 1.2939x; 1.2939x over previous
//
#include <hip/hip_runtime.h>
#include <hip/hip_fp16.h>

// DimCL encoder, R7.
//  - CSR build rewritten as two-level partition to kill k_part's 237MB
//    random-write amplification (was 228us at 1.17TB/s):
//      k_part1:   coarse multi-split (512-row bins, NC=391) with per-block
//                 LDS reorder -> bin-sorted run-coalesced writes (~50MB).
//      k_hist2:   per-ROW histogram per coarse bin (block-exclusive rows,
//                 LDS counters) -> row_cnt.
//      scan:      exclusive scan of row_cnt IS the CSR ptr (no 16-row
//                 bucket sort, no compact kernel).
//      k_scatter2: scatter records to final erec positions; each block's
//                 output is one dense ~80KB chunk (L2-resident writes).
//  - spmm: unchanged pull, one wave/row, 16 edges in flight.
//  - ws ~149 MB (fine staging + compact eliminated).
// Layers fp16, all math fp32.

#define CSH 9             // 512 rows per coarse bin
#define CBROWS (1 << CSH)
#define CAPC 12288        // coarse bin capacity (avg ~10240, ~20 sigma slack)
#define T1 4096           // edges per k_part1 block tile
#define EPT 16            // edges per thread in k_part1 (T1 = 256*EPT)
#define COLMASK 0x3FFFF   // n_nodes < 2^18

__device__ __forceinline__ int wave_iscan(int v, int lane) {
#pragma unroll
  for (int off = 1; off < 64; off <<= 1) {
    int t = __shfl_up(v, off, 64);
    if (lane >= off) v += t;
  }
  return v;
}

// init h0 (fp32->fp16) and zero the coarse-bin cursors.
__global__ __launch_bounds__(256) void k_init(
    const float* __restrict__ ue, const float* __restrict__ ie,
    __half* __restrict__ h0, int* __restrict__ ccur, int nc, int nuser_e,
    int total_e) {
  int i = blockIdx.x * 256 + threadIdx.x;
  if (i < total_e) {
    float x = (i < nuser_e) ? ue[i] : ie[i - nuser_e];
    h0[i] = __float2half(x);
  }
  if (i < nc) ccur[i] = 0;
}

// Coarse multi-split: per-block LDS histogram + scan + reserve + reorder,
// then bin-sorted (run-coalesced) copy-out to coarse staging.
// Requires NC <= 512 (n_nodes <= 262144).
__global__ __launch_bounds__(256) void k_part1(
    const int* __restrict__ rows, const int* __restrict__ cols,
    const float* __restrict__ vals, int* __restrict__ ccur,
    int2* __restrict__ cstag, int E) {
  __shared__ int cnt[512];
  __shared__ int offs[512];
  __shared__ int gbase[512];
  __shared__ int lcur[512];
  __shared__ int wsum4[4];
  __shared__ int2 sout[T1];
  __shared__ unsigned short sbin[T1];
  int tid = threadIdx.x;
  int lane = tid & 63, wid = tid >> 6;
  int base = blockIdx.x * T1;

  cnt[tid] = 0;
  cnt[tid + 256] = 0;
  __syncthreads();

  int recx[EPT], recy[EPT], rbin[EPT];
#pragma unroll
  for (int k = 0; k < EPT; ++k) {
    int idx = base + k * 256 + tid;
    if (idx < E) {
      int r = rows[idx];
      int b = r >> CSH;
      recx[k] = cols[idx] | ((r & (CBROWS - 1)) << 18);
      recy[k] = __float_as_int(vals[idx]);
      rbin[k] = b;
      atomicAdd(&cnt[b], 1);
    } else {
      rbin[k] = -1;
    }
  }
  __syncthreads();

  // exclusive scan of 512 counters: thread t owns slots 2t, 2t+1.
  int c0 = cnt[2 * tid], c1 = cnt[2 * tid + 1];
  int s = c0 + c1;
  int incl = wave_iscan(s, lane);
  if (lane == 63) wsum4[wid] = incl;
  __syncthreads();
  int woff = 0;
#pragma unroll
  for (int j = 0; j < 3; ++j)
    if (j < wid) woff += wsum4[j];
  incl += woff;
  int e0 = incl - s;
  offs[2 * tid] = e0;
  offs[2 * tid + 1] = e0 + c0;
  lcur[2 * tid] = e0;
  lcur[2 * tid + 1] = e0 + c0;
  __syncthreads();

  // reserve contiguous global ranges per bin (few hundred atomics/block).
  for (int t = tid; t < 512; t += 256) {
    int c = cnt[t];
    if (c > 0) gbase[t] = atomicAdd(&ccur[t], c);
  }
  // bin-sorted reorder into LDS.
#pragma unroll
  for (int k = 0; k < EPT; ++k) {
    if (rbin[k] >= 0) {
      int p = atomicAdd(&lcur[rbin[k]], 1);
      sout[p] = make_int2(recx[k], recy[k]);
      sbin[p] = (unsigned short)rbin[k];
    }
  }
  __syncthreads();

  // run-coalesced copy-out: consecutive i -> same bin -> consecutive addrs.
  int m = min(T1, E - base);
  for (int i = tid; i < m; i += 256) {
    int b = sbin[i];
    int rel = gbase[b] + (i - offs[b]);
    if (rel < CAPC) cstag[(size_t)b * CAPC + rel] = sout[i];
  }
}

// Per-row histogram of one coarse bin (rows are block-exclusive).
__global__ __launch_bounds__(512) void k_hist2(
    const int2* __restrict__ cstag, const int* __restrict__ ccur,
    int* __restrict__ rcnt, int n_nodes) {
  __shared__ int h[CBROWS];
  int b = blockIdx.x;
  int tid = threadIdx.x;
  h[tid] = 0;
  __syncthreads();
  int c = min(ccur[b], CAPC);
  const int2* p = cstag + (size_t)b * CAPC;
  for (int i = tid; i < c; i += 1024) {
    int x0 = p[i].x;
    int i1 = i + 512;
    int x1 = (i1 < c) ? p[i1].x : -1;
    atomicAdd(&h[x0 >> 18], 1);
    if (x1 >= 0) atomicAdd(&h[x1 >> 18], 1);
  }
  __syncthreads();
  int row = (b << CSH) + tid;
  if (row < n_nodes) rcnt[row] = h[tid];
}

// Phase 1: per-1024-chunk exclusive scan of row counts (non-destructive).
__global__ __launch_bounds__(1024) void k_scan1(
    const int* __restrict__ cnt, int* __restrict__ base, int* __restrict__ bsum,
    int n) {
  __shared__ int wsum[16];
  int i = blockIdx.x * 1024 + threadIdx.x;
  int lane = threadIdx.x & 63, wid = threadIdx.x >> 6;
  int v = (i < n) ? cnt[i] : 0;
  int incl = wave_iscan(v, lane);
  if (lane == 63) wsum[wid] = incl;
  __syncthreads();
  if (wid == 0) {
    int s = (lane < 16) ? wsum[lane] : 0;
    s = wave_iscan(s, lane);
    if (lane < 16) wsum[lane] = s;
  }
  __syncthreads();
  int woff = wid ? wsum[wid - 1] : 0;
  incl += woff;
  if (i < n) base[i] = incl - v;
  if (threadIdx.x == 1023) bsum[blockIdx.x] = incl;
}

// Phase 2: single-block exclusive scan of chunk totals (nChunks <= 1024).
__global__ __launch_bounds__(1024) void k_scan2(int* __restrict__ b, int nb) {
  __shared__ int wsum[16];
  int i = threadIdx.x;
  int lane = i & 63, wid = i >> 6;
  int v = (i < nb) ? b[i] : 0;
  int incl = wave_iscan(v, lane);
  if (lane == 63) wsum[wid] = incl;
  __syncthreads();
  if (wid == 0) {
    int s = (lane < 16) ? wsum[lane] : 0;
    s = wave_iscan(s, lane);
    if (lane < 16) wsum[lane] = s;
  }
  __syncthreads();
  int woff = wid ? wsum[wid - 1] : 0;
  if (i < nb) b[i] = (incl + woff) - v;
}

// Phase 3: add chunk offsets. base[] IS the CSR ptr.
__global__ __launch_bounds__(256) void k_scan3(
    int* __restrict__ base, const int* __restrict__ bsum, int n, int E) {
  int i = blockIdx.x * 256 + threadIdx.x;
  if (i < n) base[i] += bsum[i >> 10];
  if (i == 0) base[n] = E;
}

// Scatter coarse-bin records to final CSR positions. Each block's output is
// one dense contiguous chunk of erec (~80KB) -> L2-resident writes.
__global__ __launch_bounds__(512) void k_scatter2(
    const int2* __restrict__ cstag, const int* __restrict__ ccur,
    const int* __restrict__ ptr, int2* __restrict__ erec, int n_nodes) {
  __shared__ int lcur[CBROWS];
  int b = blockIdx.x;
  int tid = threadIdx.x;
  int row = (b << CSH) + tid;
  lcur[tid] = (row < n_nodes) ? ptr[row] : 0;
  __syncthreads();
  int c = min(ccur[b], CAPC);
  const int2* p = cstag + (size_t)b * CAPC;
  for (int i = tid; i < c; i += 1024) {
    int2 r0 = p[i];
    int i1 = i + 512;
    bool v1 = i1 < c;
    int2 r1 = v1 ? p[i1] : make_int2(0, 0);
    int pos0 = atomicAdd(&lcur[r0.x >> 18], 1);
    erec[pos0] = make_int2(r0.x & COLMASK, r0.y);
    if (v1) {
      int pos1 = atomicAdd(&lcur[r1.x >> 18], 1);
      erec[pos1] = make_int2(r1.x & COLMASK, r1.y);
    }
  }
}

// Pull-SpMM: one wave per row; lane = slot(0..3) x chquad(0..15).
// 16 edges (4 per slot) in flight per iteration; private fp32 accumulators;
// one shfl_xor cross-slot reduction per row.
__global__ __launch_bounds__(256) void k_spmm_pull(
    const __half* __restrict__ cur, __half* __restrict__ nxt,
    const int* __restrict__ ptr, const int2* __restrict__ erec, int n) {
  int w = (blockIdx.x * 256 + threadIdx.x) >> 6;
  int lane = threadIdx.x & 63;
  if (w >= n) return;
  int start = ptr[w], end = ptr[w + 1];
  int sub = lane >> 4;
  int ch = (lane & 15) << 2;
  float a0 = 0.f, a1 = 0.f, a2 = 0.f, a3 = 0.f;
  float b0 = 0.f, b1 = 0.f, b2 = 0.f, b3 = 0.f;
  const int2 zrec = {0, 0};
  for (int j = start; j < end; j += 16) {
    int j0 = j + sub, j1 = j + 4 + sub, j2 = j + 8 + sub, j3 = j + 12 + sub;
    int2 r0 = (j0 < end) ? erec[j0] : zrec;
    int2 r1 = (j1 < end) ? erec[j1] : zrec;
    int2 r2 = (j2 < end) ? erec[j2] : zrec;
    int2 r3 = (j3 < end) ? erec[j3] : zrec;
    int2 g0 = *(const int2*)(cur + ((size_t)r0.x << 6) + ch);
    int2 g1 = *(const int2*)(cur + ((size_t)r1.x << 6) + ch);
    int2 g2 = *(const int2*)(cur + ((size_t)r2.x << 6) + ch);
    int2 g3 = *(const int2*)(cur + ((size_t)r3.x << 6) + ch);
    float v0 = __int_as_float(r0.y), v1 = __int_as_float(r1.y);
    float v2 = __int_as_float(r2.y), v3 = __int_as_float(r3.y);
    __half2 p0a = *reinterpret_cast<__half2*>(&g0.x);
    __half2 p0b = *reinterpret_cast<__half2*>(&g0.y);
    __half2 p1a = *reinterpret_cast<__half2*>(&g1.x);
    __half2 p1b = *reinterpret_cast<__half2*>(&g1.y);
    __half2 p2a = *reinterpret_cast<__half2*>(&g2.x);
    __half2 p2b = *reinterpret_cast<__half2*>(&g2.y);
    __half2 p3a = *reinterpret_cast<__half2*>(&g3.x);
    __half2 p3b = *reinterpret_cast<__half2*>(&g3.y);
    float2 f0a = __half22float2(p0a), f0b = __half22float2(p0b);
    float2 f1a = __half22float2(p1a), f1b = __half22float2(p1b);
    float2 f2a = __half22float2(p2a), f2b = __half22float2(p2b);
    float2 f3a = __half22float2(p3a), f3b = __half22float2(p3b);
    a0 += v0 * f0a.x; a1 += v0 * f0a.y; a2 += v0 * f0b.x; a3 += v0 * f0b.y;
    b0 += v1 * f1a.x; b1 += v1 * f1a.y; b2 += v1 * f1b.x; b3 += v1 * f1b.y;
    a0 += v2 * f2a.x; a1 += v2 * f2a.y; a2 += v2 * f2b.x; a3 += v2 * f2b.y;
    b0 += v3 * f3a.x; b1 += v3 * f3a.y; b2 += v3 * f3b.x; b3 += v3 * f3b.y;
  }
  a0 += b0; a1 += b1; a2 += b2; a3 += b3;
  a0 += __shfl_xor(a0, 16, 64); a0 += __shfl_xor(a0, 32, 64);
  a1 += __shfl_xor(a1, 16, 64); a1 += __shfl_xor(a1, 32, 64);
  a2 += __shfl_xor(a2, 16, 64); a2 += __shfl_xor(a2, 32, 64);
  a3 += __shfl_xor(a3, 16, 64); a3 += __shfl_xor(a3, 32, 64);
  if (sub == 0) {
    __half2 lo = __halves2half2(__float2half(a0), __float2half(a1));
    __half2 hi = __halves2half2(__float2half(a2), __float2half(a3));
    int2 o;
    o.x = *reinterpret_cast<int*>(&lo);
    o.y = *reinterpret_cast<int*>(&hi);
    *reinterpret_cast<int2*>(nxt + ((size_t)w << 6) + ch) = o;
  }
}

__global__ __launch_bounds__(256) void k_fin(
    const __half* __restrict__ h1, const __half* __restrict__ h2,
    const __half* __restrict__ h3, float* __restrict__ out, int n,
    float scale) {
  int i = blockIdx.x * 256 + threadIdx.x;
  if (i < n) {
    float s = __half2float(h1[i]) + __half2float(h2[i]) + __half2float(h3[i]);
    out[i] = s * scale;
  }
}

extern "C" void kernel_launch(void* const* d_in, const int* in_sizes, int n_in,
                              void* d_out, int out_size, void* d_ws,
                              size_t ws_size, hipStream_t stream) {
  const float* ue = (const float*)d_in[0];
  const float* ie = (const float*)d_in[1];
  const float* vals = (const float*)d_in[2];
  const int* rows = (const int*)d_in[3];
  const int* cols = (const int*)d_in[4];
  const int n_layers = 3;  // fixed by problem definition

  const int EMB = 64;
  const int n_users = in_sizes[0] / EMB;
  const int n_items = in_sizes[1] / EMB;
  const int n_nodes = n_users + n_items;
  const int E = in_sizes[2];
  const int total_e = n_nodes * EMB;
  const int NC = (n_nodes + CBROWS - 1) >> CSH;  // coarse bins (<=512)

  // Workspace layout (~149 MB)
  __half* h0 = (__half*)d_ws;           // ego; later reused for layer-3 out
  __half* h1 = h0 + total_e;
  __half* h2 = h1 + total_e;
  int2* erec = (int2*)(h2 + total_e);   // final CSR records [E]
  int2* cstag = erec + E;               // coarse staging [NC*CAPC]
  int* ccur = (int*)(cstag + (size_t)NC * CAPC);  // coarse cursors [NC]
  int* rcnt = ccur + NC + 8;            // per-row counts [n_nodes]
  int* ptr = rcnt + n_nodes + 8;        // CSR row_ptr [n_nodes+1]
  int* bsum = ptr + n_nodes + 8;        // scan chunk totals

  const int gElem = (total_e + 255) / 256;
  const int gP1 = (E + T1 - 1) / T1;
  const int nChunks = (n_nodes + 1023) / 1024;
  const int gSpmm = (n_nodes + 3) / 4;

  // --- build ---
  k_init<<<gElem, 256, 0, stream>>>(ue, ie, h0, ccur, NC, n_users * EMB,
                                    total_e);
  k_part1<<<gP1, 256, 0, stream>>>(rows, cols, vals, ccur, cstag, E);
  k_hist2<<<NC, 512, 0, stream>>>(cstag, ccur, rcnt, n_nodes);
  k_scan1<<<nChunks, 1024, 0, stream>>>(rcnt, ptr, bsum, n_nodes);
  k_scan2<<<1, 1024, 0, stream>>>(bsum, nChunks);
  k_scan3<<<(n_nodes + 255) / 256, 256, 0, stream>>>(ptr, bsum, n_nodes, E);
  k_scatter2<<<NC, 512, 0, stream>>>(cstag, ccur, ptr, erec, n_nodes);

  // --- propagation (layer3 output reuses h0) ---
  __half* layers[4] = {h0, h1, h2, h0};
  for (int l = 0; l < n_layers; ++l) {
    k_spmm_pull<<<gSpmm, 256, 0, stream>>>(layers[l], layers[l + 1], ptr, erec,
                                           n_nodes);
  }
  k_fin<<<gElem, 256, 0, stream>>>(h1, h2, h0, (float*)d_out, total_e,
                                   1.0f / (float)n_layers);
}

// Round 2
// 549.589 us; speedup vs baseline: 1.3748x; 1.0626x over previous
//
#include <hip/hip_runtime.h>
#include <hip/hip_fp16.h>

// DimCL encoder, R8.
//  - CSR build (R7 two-level partition) unchanged:
//      k_part1 -> coarse 512-row bins, k_hist2 per-row hist, scan -> ptr,
//      k_scatter2 -> final erec (L2-resident writes).
//  - spmm deepened: 32 edges in flight per wave (8 record + 8 gather loads
//    outstanding per slot), unguarded record loads (tail reads allocated
//    staging; col masked, val cndmask'd), ~1 iteration per avg row.
//  - k_fin fused into layer-3 spmm epilogue: layer-3 row sums stay in fp32
//    registers, h1/h2 read in-kernel, fp32 output written directly.
//    Saves h3 store + h3 read + one launch.
// Layers fp16, all math fp32.

#define CSH 9             // 512 rows per coarse bin
#define CBROWS (1 << CSH)
#define CAPC 12288        // coarse bin capacity (avg ~10240, ~20 sigma slack)
#define T1 4096           // edges per k_part1 block tile
#define EPT 16            // edges per thread in k_part1 (T1 = 256*EPT)
#define COLMASK 0x3FFFF   // n_nodes < 2^18

__device__ __forceinline__ int wave_iscan(int v, int lane) {
#pragma unroll
  for (int off = 1; off < 64; off <<= 1) {
    int t = __shfl_up(v, off, 64);
    if (lane >= off) v += t;
  }
  return v;
}

// init h0 (fp32->fp16) and zero the coarse-bin cursors.
__global__ __launch_bounds__(256) void k_init(
    const float* __restrict__ ue, const float* __restrict__ ie,
    __half* __restrict__ h0, int* __restrict__ ccur, int nc, int nuser_e,
    int total_e) {
  int i = blockIdx.x * 256 + threadIdx.x;
  if (i < total_e) {
    float x = (i < nuser_e) ? ue[i] : ie[i - nuser_e];
    h0[i] = __float2half(x);
  }
  if (i < nc) ccur[i] = 0;
}

// Coarse multi-split: per-block LDS histogram + scan + reserve + reorder,
// then bin-sorted (run-coalesced) copy-out to coarse staging.
// Requires NC <= 512 (n_nodes <= 262144).
__global__ __launch_bounds__(256) void k_part1(
    const int* __restrict__ rows, const int* __restrict__ cols,
    const float* __restrict__ vals, int* __restrict__ ccur,
    int2* __restrict__ cstag, int E) {
  __shared__ int cnt[512];
  __shared__ int offs[512];
  __shared__ int gbase[512];
  __shared__ int lcur[512];
  __shared__ int wsum4[4];
  __shared__ int2 sout[T1];
  __shared__ unsigned short sbin[T1];
  int tid = threadIdx.x;
  int lane = tid & 63, wid = tid >> 6;
  int base = blockIdx.x * T1;

  cnt[tid] = 0;
  cnt[tid + 256] = 0;
  __syncthreads();

  int recx[EPT], recy[EPT], rbin[EPT];
#pragma unroll
  for (int k = 0; k < EPT; ++k) {
    int idx = base + k * 256 + tid;
    if (idx < E) {
      int r = rows[idx];
      int b = r >> CSH;
      recx[k] = cols[idx] | ((r & (CBROWS - 1)) << 18);
      recy[k] = __float_as_int(vals[idx]);
      rbin[k] = b;
      atomicAdd(&cnt[b], 1);
    } else {
      rbin[k] = -1;
    }
  }
  __syncthreads();

  // exclusive scan of 512 counters: thread t owns slots 2t, 2t+1.
  int c0 = cnt[2 * tid], c1 = cnt[2 * tid + 1];
  int s = c0 + c1;
  int incl = wave_iscan(s, lane);
  if (lane == 63) wsum4[wid] = incl;
  __syncthreads();
  int woff = 0;
#pragma unroll
  for (int j = 0; j < 3; ++j)
    if (j < wid) woff += wsum4[j];
  incl += woff;
  int e0 = incl - s;
  offs[2 * tid] = e0;
  offs[2 * tid + 1] = e0 + c0;
  lcur[2 * tid] = e0;
  lcur[2 * tid + 1] = e0 + c0;
  __syncthreads();

  // reserve contiguous global ranges per bin (few hundred atomics/block).
  for (int t = tid; t < 512; t += 256) {
    int c = cnt[t];
    if (c > 0) gbase[t] = atomicAdd(&ccur[t], c);
  }
  // bin-sorted reorder into LDS.
#pragma unroll
  for (int k = 0; k < EPT; ++k) {
    if (rbin[k] >= 0) {
      int p = atomicAdd(&lcur[rbin[k]], 1);
      sout[p] = make_int2(recx[k], recy[k]);
      sbin[p] = (unsigned short)rbin[k];
    }
  }
  __syncthreads();

  // run-coalesced copy-out: consecutive i -> same bin -> consecutive addrs.
  int m = min(T1, E - base);
  for (int i = tid; i < m; i += 256) {
    int b = sbin[i];
    int rel = gbase[b] + (i - offs[b]);
    if (rel < CAPC) cstag[(size_t)b * CAPC + rel] = sout[i];
  }
}

// Per-row histogram of one coarse bin (rows are block-exclusive).
__global__ __launch_bounds__(512) void k_hist2(
    const int2* __restrict__ cstag, const int* __restrict__ ccur,
    int* __restrict__ rcnt, int n_nodes) {
  __shared__ int h[CBROWS];
  int b = blockIdx.x;
  int tid = threadIdx.x;
  h[tid] = 0;
  __syncthreads();
  int c = min(ccur[b], CAPC);
  const int2* p = cstag + (size_t)b * CAPC;
  for (int i = tid; i < c; i += 1024) {
    int x0 = p[i].x;
    int i1 = i + 512;
    int x1 = (i1 < c) ? p[i1].x : -1;
    atomicAdd(&h[x0 >> 18], 1);
    if (x1 >= 0) atomicAdd(&h[x1 >> 18], 1);
  }
  __syncthreads();
  int row = (b << CSH) + tid;
  if (row < n_nodes) rcnt[row] = h[tid];
}

// Phase 1: per-1024-chunk exclusive scan of row counts (non-destructive).
__global__ __launch_bounds__(1024) void k_scan1(
    const int* __restrict__ cnt, int* __restrict__ base, int* __restrict__ bsum,
    int n) {
  __shared__ int wsum[16];
  int i = blockIdx.x * 1024 + threadIdx.x;
  int lane = threadIdx.x & 63, wid = threadIdx.x >> 6;
  int v = (i < n) ? cnt[i] : 0;
  int incl = wave_iscan(v, lane);
  if (lane == 63) wsum[wid] = incl;
  __syncthreads();
  if (wid == 0) {
    int s = (lane < 16) ? wsum[lane] : 0;
    s = wave_iscan(s, lane);
    if (lane < 16) wsum[lane] = s;
  }
  __syncthreads();
  int woff = wid ? wsum[wid - 1] : 0;
  incl += woff;
  if (i < n) base[i] = incl - v;
  if (threadIdx.x == 1023) bsum[blockIdx.x] = incl;
}

// Phase 2: single-block exclusive scan of chunk totals (nChunks <= 1024).
__global__ __launch_bounds__(1024) void k_scan2(int* __restrict__ b, int nb) {
  __shared__ int wsum[16];
  int i = threadIdx.x;
  int lane = i & 63, wid = i >> 6;
  int v = (i < nb) ? b[i] : 0;
  int incl = wave_iscan(v, lane);
  if (lane == 63) wsum[wid] = incl;
  __syncthreads();
  if (wid == 0) {
    int s = (lane < 16) ? wsum[lane] : 0;
    s = wave_iscan(s, lane);
    if (lane < 16) wsum[lane] = s;
  }
  __syncthreads();
  int woff = wid ? wsum[wid - 1] : 0;
  if (i < nb) b[i] = (incl + woff) - v;
}

// Phase 3: add chunk offsets. base[] IS the CSR ptr.
__global__ __launch_bounds__(256) void k_scan3(
    int* __restrict__ base, const int* __restrict__ bsum, int n, int E) {
  int i = blockIdx.x * 256 + threadIdx.x;
  if (i < n) base[i] += bsum[i >> 10];
  if (i == 0) base[n] = E;
}

// Scatter coarse-bin records to final CSR positions. Each block's output is
// one dense contiguous chunk of erec (~80KB) -> L2-resident writes.
__global__ __launch_bounds__(512) void k_scatter2(
    const int2* __restrict__ cstag, const int* __restrict__ ccur,
    const int* __restrict__ ptr, int2* __restrict__ erec, int n_nodes) {
  __shared__ int lcur[CBROWS];
  int b = blockIdx.x;
  int tid = threadIdx.x;
  int row = (b << CSH) + tid;
  lcur[tid] = (row < n_nodes) ? ptr[row] : 0;
  __syncthreads();
  int c = min(ccur[b], CAPC);
  const int2* p = cstag + (size_t)b * CAPC;
  for (int i = tid; i < c; i += 1024) {
    int2 r0 = p[i];
    int i1 = i + 512;
    bool v1 = i1 < c;
    int2 r1 = v1 ? p[i1] : make_int2(0, 0);
    int pos0 = atomicAdd(&lcur[r0.x >> 18], 1);
    erec[pos0] = make_int2(r0.x & COLMASK, r0.y);
    if (v1) {
      int pos1 = atomicAdd(&lcur[r1.x >> 18], 1);
      erec[pos1] = make_int2(r1.x & COLMASK, r1.y);
    }
  }
}

// Pull-SpMM: one wave per row; lane = slot(0..3) x chquad(0..15).
// 32 edges (8 per slot) in flight per iteration; record loads unguarded
// (reads past `end` land in allocated staging; col re-masked, val zeroed by
// cndmask). FIN: layer-3 sums stay fp32 in regs; epilogue fuses the
// (h1+h2+h3)/3 mean and writes fp32 output directly.
template <bool FIN>
__global__ __launch_bounds__(256) void k_spmm(
    const __half* __restrict__ cur, __half* __restrict__ nxt,
    const __half* __restrict__ h1, const __half* __restrict__ h2,
    float* __restrict__ out, const int* __restrict__ ptr,
    const int2* __restrict__ erec, int n, float scale) {
  int w = (blockIdx.x * 256 + threadIdx.x) >> 6;
  int lane = threadIdx.x & 63;
  if (w >= n) return;
  int start = ptr[w], end = ptr[w + 1];
  int sub = lane >> 4;
  int ch = (lane & 15) << 2;  // half-offset within the 64-wide row
  float a0 = 0.f, a1 = 0.f, a2 = 0.f, a3 = 0.f;
  float b0 = 0.f, b1 = 0.f, b2 = 0.f, b3 = 0.f;
  for (int j = start; j < end; j += 32) {
    int2 r[8];
#pragma unroll
    for (int k = 0; k < 8; ++k) r[k] = erec[j + sub + 4 * k];
    int off[8];
    float v[8];
#pragma unroll
    for (int k = 0; k < 8; ++k) {
      off[k] = ((r[k].x & COLMASK) << 6) + ch;
      v[k] = (j + sub + 4 * k < end) ? __int_as_float(r[k].y) : 0.f;
    }
    int2 g[8];
#pragma unroll
    for (int k = 0; k < 8; ++k) g[k] = *(const int2*)(cur + off[k]);
#pragma unroll
    for (int k = 0; k < 8; ++k) {
      float2 fa = __half22float2(*reinterpret_cast<__half2*>(&g[k].x));
      float2 fb = __half22float2(*reinterpret_cast<__half2*>(&g[k].y));
      if (k & 1) {
        b0 += v[k] * fa.x; b1 += v[k] * fa.y;
        b2 += v[k] * fb.x; b3 += v[k] * fb.y;
      } else {
        a0 += v[k] * fa.x; a1 += v[k] * fa.y;
        a2 += v[k] * fb.x; a3 += v[k] * fb.y;
      }
    }
  }
  a0 += b0; a1 += b1; a2 += b2; a3 += b3;
  a0 += __shfl_xor(a0, 16, 64); a0 += __shfl_xor(a0, 32, 64);
  a1 += __shfl_xor(a1, 16, 64); a1 += __shfl_xor(a1, 32, 64);
  a2 += __shfl_xor(a2, 16, 64); a2 += __shfl_xor(a2, 32, 64);
  a3 += __shfl_xor(a3, 16, 64); a3 += __shfl_xor(a3, 32, 64);
  if (sub == 0) {
    size_t o = ((size_t)w << 6) + ch;
    if (!FIN) {
      __half2 lo = __halves2half2(__float2half(a0), __float2half(a1));
      __half2 hi = __halves2half2(__float2half(a2), __float2half(a3));
      int2 pk;
      pk.x = *reinterpret_cast<int*>(&lo);
      pk.y = *reinterpret_cast<int*>(&hi);
      *reinterpret_cast<int2*>(nxt + o) = pk;
    } else {
      int2 x1 = *(const int2*)(h1 + o);
      int2 x2 = *(const int2*)(h2 + o);
      float2 u1a = __half22float2(*reinterpret_cast<__half2*>(&x1.x));
      float2 u1b = __half22float2(*reinterpret_cast<__half2*>(&x1.y));
      float2 u2a = __half22float2(*reinterpret_cast<__half2*>(&x2.x));
      float2 u2b = __half22float2(*reinterpret_cast<__half2*>(&x2.y));
      float4 r;
      r.x = (u1a.x + u2a.x + a0) * scale;
      r.y = (u1a.y + u2a.y + a1) * scale;
      r.z = (u1b.x + u2b.x + a2) * scale;
      r.w = (u1b.y + u2b.y + a3) * scale;
      *reinterpret_cast<float4*>(out + o) = r;
    }
  }
}

extern "C" void kernel_launch(void* const* d_in, const int* in_sizes, int n_in,
                              void* d_out, int out_size, void* d_ws,
                              size_t ws_size, hipStream_t stream) {
  const float* ue = (const float*)d_in[0];
  const float* ie = (const float*)d_in[1];
  const float* vals = (const float*)d_in[2];
  const int* rows = (const int*)d_in[3];
  const int* cols = (const int*)d_in[4];
  const int n_layers = 3;  // fixed by problem definition
  (void)n_layers;

  const int EMB = 64;
  const int n_users = in_sizes[0] / EMB;
  const int n_items = in_sizes[1] / EMB;
  const int n_nodes = n_users + n_items;
  const int E = in_sizes[2];
  const int total_e = n_nodes * EMB;
  const int NC = (n_nodes + CBROWS - 1) >> CSH;  // coarse bins (<=512)

  // Workspace layout (~149 MB). NOTE: spmm record loads may read up to 31
  // records past erec[E-1]; those land inside cstag (allocated) and their
  // values are masked out, cols re-masked -- no OOB, no NaN.
  __half* h0 = (__half*)d_ws;           // ego
  __half* h1 = h0 + total_e;
  __half* h2 = h1 + total_e;
  int2* erec = (int2*)(h2 + total_e);   // final CSR records [E]
  int2* cstag = erec + E;               // coarse staging [NC*CAPC]
  int* ccur = (int*)(cstag + (size_t)NC * CAPC);  // coarse cursors [NC]
  int* rcnt = ccur + NC + 8;            // per-row counts [n_nodes]
  int* ptr = rcnt + n_nodes + 8;        // CSR row_ptr [n_nodes+1]
  int* bsum = ptr + n_nodes + 8;        // scan chunk totals

  const int gElem = (total_e + 255) / 256;
  const int gP1 = (E + T1 - 1) / T1;
  const int nChunks = (n_nodes + 1023) / 1024;
  const int gSpmm = (n_nodes + 3) / 4;

  // --- build ---
  k_init<<<gElem, 256, 0, stream>>>(ue, ie, h0, ccur, NC, n_users * EMB,
                                    total_e);
  k_part1<<<gP1, 256, 0, stream>>>(rows, cols, vals, ccur, cstag, E);
  k_hist2<<<NC, 512, 0, stream>>>(cstag, ccur, rcnt, n_nodes);
  k_scan1<<<nChunks, 1024, 0, stream>>>(rcnt, ptr, bsum, n_nodes);
  k_scan2<<<1, 1024, 0, stream>>>(bsum, nChunks);
  k_scan3<<<(n_nodes + 255) / 256, 256, 0, stream>>>(ptr, bsum, n_nodes, E);
  k_scatter2<<<NC, 512, 0, stream>>>(cstag, ccur, ptr, erec, n_nodes);

  // --- propagation; layer 3 fuses the mean + fp32 output write ---
  k_spmm<false><<<gSpmm, 256, 0, stream>>>(h0, h1, nullptr, nullptr, nullptr,
                                           ptr, erec, n_nodes, 0.f);
  k_spmm<false><<<gSpmm, 256, 0, stream>>>(h1, h2, nullptr, nullptr, nullptr,
                                           ptr, erec, n_nodes, 0.f);
  k_spmm<true><<<gSpmm, 256, 0, stream>>>(h2, nullptr, h1, h2, (float*)d_out,
                                          ptr, erec, n_nodes,
                                          1.0f / 3.0f);
}

// Round 3
// 537.450 us; speedup vs baseline: 1.4059x; 1.0226x over previous
//
#include <hip/hip_runtime.h>
#include <hip/hip_fp16.h>

// DimCL encoder, R9.
//  - spmm inner loop: v_fma_mix_f32 (half source, fp32 acc) via inline asm
//    -- removes the cvt chain, 4 VALU ops per gathered 8B instead of ~8.
//  - build chain collapsed: k_part1 (coarse 256-row bins) -> k_binscan
//    (1-block scan of bin counts -> bin bases, writes ptr[n]) -> k_csr
//    (fused: stage bin in LDS, per-row hist, in-block scan, scatter to
//    final erec, write ptr). Replaces hist2+scan1/2/3+scatter2: two fewer
//    passes over the 32MB staging, 10 launches -> 7.
// Layers fp16, all math fp32.

#define CSH 8             // 256 rows per coarse bin
#define CBROWS (1 << CSH)
#define CAPC 6144         // bin capacity (avg ~5120, ~14 sigma slack)
#define T1 4096           // edges per k_part1 block tile
#define EPT 16            // edges per thread in k_part1 (T1 = 256*EPT)
#define COLMASK 0x3FFFF   // n_nodes < 2^18

// acc += (float)lo_half(pk) * v   /   acc += (float)hi_half(pk) * v
#define FMAMIX_LO(acc, pk, v)                                             \
  asm("v_fma_mix_f32 %0, %1, %2, %0 op_sel:[0,0,0] op_sel_hi:[1,0,0]"     \
      : "+v"(acc)                                                         \
      : "v"(pk), "v"(v))
#define FMAMIX_HI(acc, pk, v)                                             \
  asm("v_fma_mix_f32 %0, %1, %2, %0 op_sel:[1,0,0] op_sel_hi:[1,0,0]"     \
      : "+v"(acc)                                                         \
      : "v"(pk), "v"(v))

__device__ __forceinline__ int wave_iscan(int v, int lane) {
#pragma unroll
  for (int off = 1; off < 64; off <<= 1) {
    int t = __shfl_up(v, off, 64);
    if (lane >= off) v += t;
  }
  return v;
}

// init h0 (fp32->fp16) and zero the coarse-bin cursors.
__global__ __launch_bounds__(256) void k_init(
    const float* __restrict__ ue, const float* __restrict__ ie,
    __half* __restrict__ h0, int* __restrict__ ccur, int nc, int nuser_e,
    int total_e) {
  int i = blockIdx.x * 256 + threadIdx.x;
  if (i < total_e) {
    float x = (i < nuser_e) ? ue[i] : ie[i - nuser_e];
    h0[i] = __float2half(x);
  }
  if (i < nc) ccur[i] = 0;
}

// Coarse multi-split: per-block LDS histogram + scan + reserve + reorder,
// then bin-sorted (run-coalesced) copy-out to coarse staging.
// Requires NC <= 1024 (n_nodes <= 262144).
__global__ __launch_bounds__(256) void k_part1(
    const int* __restrict__ rows, const int* __restrict__ cols,
    const float* __restrict__ vals, int* __restrict__ ccur,
    int2* __restrict__ cstag, int E) {
  __shared__ int cnt[1024];   // counts; after reserve, holds global bases
  __shared__ int offs[1024];
  __shared__ int lcur[1024];
  __shared__ int wsum4[4];
  __shared__ int2 sout[T1];
  __shared__ unsigned short sbin[T1];
  int tid = threadIdx.x;
  int lane = tid & 63, wid = tid >> 6;
  int base = blockIdx.x * T1;

#pragma unroll
  for (int j = 0; j < 4; ++j) cnt[tid + 256 * j] = 0;
  __syncthreads();

  int recx[EPT], recy[EPT], rbin[EPT];
#pragma unroll
  for (int k = 0; k < EPT; ++k) {
    int idx = base + k * 256 + tid;
    if (idx < E) {
      int r = rows[idx];
      int b = r >> CSH;
      recx[k] = cols[idx] | ((r & (CBROWS - 1)) << 18);
      recy[k] = __float_as_int(vals[idx]);
      rbin[k] = b;
      atomicAdd(&cnt[b], 1);
    } else {
      rbin[k] = -1;
    }
  }
  __syncthreads();

  // exclusive scan of 1024 counters: thread t owns slots 4t..4t+3.
  int c0 = cnt[4 * tid], c1 = cnt[4 * tid + 1];
  int c2 = cnt[4 * tid + 2], c3 = cnt[4 * tid + 3];
  int s = c0 + c1 + c2 + c3;
  int incl = wave_iscan(s, lane);
  if (lane == 63) wsum4[wid] = incl;
  __syncthreads();
  int woff = 0;
#pragma unroll
  for (int j = 0; j < 3; ++j)
    if (j < wid) woff += wsum4[j];
  incl += woff;
  int e0 = incl - s;
  offs[4 * tid] = e0;
  offs[4 * tid + 1] = e0 + c0;
  offs[4 * tid + 2] = e0 + c0 + c1;
  offs[4 * tid + 3] = e0 + c0 + c1 + c2;
  lcur[4 * tid] = e0;
  lcur[4 * tid + 1] = e0 + c0;
  lcur[4 * tid + 2] = e0 + c0 + c1;
  lcur[4 * tid + 3] = e0 + c0 + c1 + c2;
  __syncthreads();

  // reserve contiguous global ranges per bin; store base over cnt (each slot
  // read+written by the same thread -> no hazard).
#pragma unroll
  for (int j = 0; j < 4; ++j) {
    int t = tid + 256 * j;
    int c = cnt[t];
    if (c > 0) cnt[t] = atomicAdd(&ccur[t], c);
  }
  // bin-sorted reorder into LDS.
#pragma unroll
  for (int k = 0; k < EPT; ++k) {
    if (rbin[k] >= 0) {
      int p = atomicAdd(&lcur[rbin[k]], 1);
      sout[p] = make_int2(recx[k], recy[k]);
      sbin[p] = (unsigned short)rbin[k];
    }
  }
  __syncthreads();

  // run-coalesced copy-out: consecutive i -> same bin -> consecutive addrs.
  int m = min(T1, E - base);
  for (int i = tid; i < m; i += 256) {
    int b = sbin[i];
    int rel = cnt[b] + (i - offs[b]);  // cnt[] holds global base now
    if (rel < CAPC) cstag[(size_t)b * CAPC + rel] = sout[i];
  }
}

// Single-block exclusive scan of bin counts -> bin bases; also ptr[n]=E.
__global__ __launch_bounds__(1024) void k_binscan(
    const int* __restrict__ ccur, int* __restrict__ bbase,
    int* __restrict__ ptr, int nc, int n_nodes, int E) {
  __shared__ int wsum[16];
  int i = threadIdx.x;
  int lane = i & 63, wid = i >> 6;
  int v = (i < nc) ? min(ccur[i], CAPC) : 0;
  int incl = wave_iscan(v, lane);
  if (lane == 63) wsum[wid] = incl;
  __syncthreads();
  if (wid == 0) {
    int s = (lane < 16) ? wsum[lane] : 0;
    s = wave_iscan(s, lane);
    if (lane < 16) wsum[lane] = s;
  }
  __syncthreads();
  int woff = wid ? wsum[wid - 1] : 0;
  if (i < nc) bbase[i] = (incl + woff) - v;
  if (i == 0) ptr[n_nodes] = E;
}

// Fused CSR finalize: one block per bin. Stage records in LDS, per-row hist,
// in-block scan, scatter to final erec (writes land in the bin's contiguous
// ~40KB chunk -> L2-resident), write ptr for the bin's rows.
__global__ __launch_bounds__(512) void k_csr(
    const int2* __restrict__ cstag, const int* __restrict__ ccur,
    const int* __restrict__ bbase, int2* __restrict__ erec,
    int* __restrict__ ptr, int n_nodes) {
  __shared__ int2 srec[CAPC];     // 48KB
  __shared__ int hist[CBROWS];
  __shared__ int off[CBROWS];
  __shared__ int lcur[CBROWS];
  int b = blockIdx.x;
  int tid = threadIdx.x;
  int c = min(ccur[b], CAPC);
  int base = bbase[b];
  if (tid < CBROWS) hist[tid] = 0;
  __syncthreads();
  const int2* p = cstag + (size_t)b * CAPC;
  for (int i = tid; i < c; i += 512) {
    int2 r = p[i];
    srec[i] = r;
    atomicAdd(&hist[(r.x >> 18) & (CBROWS - 1)], 1);
  }
  __syncthreads();
  // exclusive scan of 256 counters by wave 0 (lane l owns slots 4l..4l+3).
  if (tid < 64) {
    int h0 = hist[4 * tid], h1 = hist[4 * tid + 1];
    int h2 = hist[4 * tid + 2], h3 = hist[4 * tid + 3];
    int s = h0 + h1 + h2 + h3;
    int incl = wave_iscan(s, tid);
    int e0 = incl - s;
    off[4 * tid] = e0;
    off[4 * tid + 1] = e0 + h0;
    off[4 * tid + 2] = e0 + h0 + h1;
    off[4 * tid + 3] = e0 + h0 + h1 + h2;
  }
  __syncthreads();
  if (tid < CBROWS) lcur[tid] = off[tid];
  __syncthreads();
  for (int i = tid; i < c; i += 512) {
    int2 r = srec[i];
    int ro = (r.x >> 18) & (CBROWS - 1);
    int pos = atomicAdd(&lcur[ro], 1);
    erec[base + pos] = make_int2(r.x & COLMASK, r.y);
  }
  int row = (b << CSH) + tid;
  if (tid < CBROWS && row < n_nodes) ptr[row] = base + off[tid];
}

// Pull-SpMM: one wave per row; lane = slot(0..3) x chquad(0..15).
// 32 edges (8 per slot) in flight per iteration; record loads unguarded
// (reads past `end` land in allocated staging; col re-masked, val zeroed).
// Inner product via v_fma_mix_f32 (fp16 source, fp32 accumulate).
// FIN: layer-3 sums stay fp32 in regs; epilogue fuses (h1+h2+h3)/3 and
// writes fp32 output directly.
template <bool FIN>
__global__ __launch_bounds__(256) void k_spmm(
    const __half* __restrict__ cur, __half* __restrict__ nxt,
    const __half* __restrict__ h1, const __half* __restrict__ h2,
    float* __restrict__ out, const int* __restrict__ ptr,
    const int2* __restrict__ erec, int n, float scale) {
  int w = (blockIdx.x * 256 + threadIdx.x) >> 6;
  int lane = threadIdx.x & 63;
  if (w >= n) return;
  int start = ptr[w], end = ptr[w + 1];
  int sub = lane >> 4;
  int ch = (lane & 15) << 2;  // half-offset within the 64-wide row
  float a0 = 0.f, a1 = 0.f, a2 = 0.f, a3 = 0.f;
  float b0 = 0.f, b1 = 0.f, b2 = 0.f, b3 = 0.f;
  for (int j = start; j < end; j += 32) {
    int2 r[8];
#pragma unroll
    for (int k = 0; k < 8; ++k) r[k] = erec[j + sub + 4 * k];
    int off[8];
    float v[8];
#pragma unroll
    for (int k = 0; k < 8; ++k) {
      off[k] = ((r[k].x & COLMASK) << 6) + ch;
      v[k] = (j + sub + 4 * k < end) ? __int_as_float(r[k].y) : 0.f;
    }
    int2 g[8];
#pragma unroll
    for (int k = 0; k < 8; ++k) g[k] = *(const int2*)(cur + off[k]);
#pragma unroll
    for (int k = 0; k < 8; ++k) {
      if (k & 1) {
        FMAMIX_LO(b0, g[k].x, v[k]);
        FMAMIX_HI(b1, g[k].x, v[k]);
        FMAMIX_LO(b2, g[k].y, v[k]);
        FMAMIX_HI(b3, g[k].y, v[k]);
      } else {
        FMAMIX_LO(a0, g[k].x, v[k]);
        FMAMIX_HI(a1, g[k].x, v[k]);
        FMAMIX_LO(a2, g[k].y, v[k]);
        FMAMIX_HI(a3, g[k].y, v[k]);
      }
    }
  }
  a0 += b0; a1 += b1; a2 += b2; a3 += b3;
  a0 += __shfl_xor(a0, 16, 64); a0 += __shfl_xor(a0, 32, 64);
  a1 += __shfl_xor(a1, 16, 64); a1 += __shfl_xor(a1, 32, 64);
  a2 += __shfl_xor(a2, 16, 64); a2 += __shfl_xor(a2, 32, 64);
  a3 += __shfl_xor(a3, 16, 64); a3 += __shfl_xor(a3, 32, 64);
  if (sub == 0) {
    size_t o = ((size_t)w << 6) + ch;
    if (!FIN) {
      __half2 lo = __halves2half2(__float2half(a0), __float2half(a1));
      __half2 hi = __halves2half2(__float2half(a2), __float2half(a3));
      int2 pk;
      pk.x = *reinterpret_cast<int*>(&lo);
      pk.y = *reinterpret_cast<int*>(&hi);
      *reinterpret_cast<int2*>(nxt + o) = pk;
    } else {
      int2 x1 = *(const int2*)(h1 + o);
      int2 x2 = *(const int2*)(h2 + o);
      float2 u1a = __half22float2(*reinterpret_cast<__half2*>(&x1.x));
      float2 u1b = __half22float2(*reinterpret_cast<__half2*>(&x1.y));
      float2 u2a = __half22float2(*reinterpret_cast<__half2*>(&x2.x));
      float2 u2b = __half22float2(*reinterpret_cast<__half2*>(&x2.y));
      float4 r;
      r.x = (u1a.x + u2a.x + a0) * scale;
      r.y = (u1a.y + u2a.y + a1) * scale;
      r.z = (u1b.x + u2b.x + a2) * scale;
      r.w = (u1b.y + u2b.y + a3) * scale;
      *reinterpret_cast<float4*>(out + o) = r;
    }
  }
}

extern "C" void kernel_launch(void* const* d_in, const int* in_sizes, int n_in,
                              void* d_out, int out_size, void* d_ws,
                              size_t ws_size, hipStream_t stream) {
  const float* ue = (const float*)d_in[0];
  const float* ie = (const float*)d_in[1];
  const float* vals = (const float*)d_in[2];
  const int* rows = (const int*)d_in[3];
  const int* cols = (const int*)d_in[4];

  const int EMB = 64;
  const int n_users = in_sizes[0] / EMB;
  const int n_items = in_sizes[1] / EMB;
  const int n_nodes = n_users + n_items;
  const int E = in_sizes[2];
  const int total_e = n_nodes * EMB;
  const int NC = (n_nodes + CBROWS - 1) >> CSH;  // coarse bins (<=1024)

  // Workspace layout (~148 MB). NOTE: spmm record loads may read up to 31
  // records past erec[E-1]; those land inside cstag (allocated) and their
  // values are masked out, cols re-masked -- no OOB, no NaN.
  __half* h0 = (__half*)d_ws;           // ego
  __half* h1 = h0 + total_e;
  __half* h2 = h1 + total_e;
  int2* erec = (int2*)(h2 + total_e);   // final CSR records [E]
  int2* cstag = erec + E;               // coarse staging [NC*CAPC]
  int* ccur = (int*)(cstag + (size_t)NC * CAPC);  // coarse cursors [NC]
  int* bbase = ccur + NC + 8;           // bin bases [NC]
  int* ptr = bbase + NC + 8;            // CSR row_ptr [n_nodes+1]

  const int gElem = (total_e + 255) / 256;
  const int gP1 = (E + T1 - 1) / T1;
  const int gSpmm = (n_nodes + 3) / 4;

  // --- build ---
  k_init<<<gElem, 256, 0, stream>>>(ue, ie, h0, ccur, NC, n_users * EMB,
                                    total_e);
  k_part1<<<gP1, 256, 0, stream>>>(rows, cols, vals, ccur, cstag, E);
  k_binscan<<<1, 1024, 0, stream>>>(ccur, bbase, ptr, NC, n_nodes, E);
  k_csr<<<NC, 512, 0, stream>>>(cstag, ccur, bbase, erec, ptr, n_nodes);

  // --- propagation; layer 3 fuses the mean + fp32 output write ---
  k_spmm<false><<<gSpmm, 256, 0, stream>>>(h0, h1, nullptr, nullptr, nullptr,
                                           ptr, erec, n_nodes, 0.f);
  k_spmm<false><<<gSpmm, 256, 0, stream>>>(h1, h2, nullptr, nullptr, nullptr,
                                           ptr, erec, n_nodes, 0.f);
  k_spmm<true><<<gSpmm, 256, 0, stream>>>(h2, nullptr, h1, h2, (float*)d_out,
                                          ptr, erec, n_nodes, 1.0f / 3.0f);
}

// Round 4
// 535.413 us; speedup vs baseline: 1.4112x; 1.0038x over previous
//
#include <hip/hip_runtime.h>
#include <hip/hip_fp16.h>

// DimCL encoder, R10.
//  - spmm: 32 edges in flight kept, but phantom slots (past row end) get
//    their gather OFFSET masked to row 0 (L1-hot) -- kills the ~2.4M/layer
//    phantom random gathers that R8/R9's unguarded loads issued (R7's
//    16-deep guarded form was faster than R9's 32-deep for this reason).
//    Bijective XCD swizzle on blocks: contiguous row ranges per XCD.
//  - k_part1: 512 threads/block (EPT=8, same T1=4096 tile -> same global
//    atomic count), 24 waves/CU instead of 12; ego fp32->fp16 convert fused
//    into its prologue (k_init removed; cursor zeroing via hipMemsetAsync).
//  - k_csr: staging read as int4 (2 records per load).
// Layers fp16, all math fp32.

#define CSH 8             // 256 rows per coarse bin
#define CBROWS (1 << CSH)
#define CAPC 6144         // bin capacity (avg ~5120, ~14 sigma slack)
#define T1 4096           // edges per k_part1 block tile
#define EPT 8             // edges per thread in k_part1 (T1 = 512*EPT)
#define COLMASK 0x3FFFF   // n_nodes < 2^18

// acc += (float)lo_half(pk) * v   /   acc += (float)hi_half(pk) * v
#define FMAMIX_LO(acc, pk, v)                                             \
  asm("v_fma_mix_f32 %0, %1, %2, %0 op_sel:[0,0,0] op_sel_hi:[1,0,0]"     \
      : "+v"(acc)                                                         \
      : "v"(pk), "v"(v))
#define FMAMIX_HI(acc, pk, v)                                             \
  asm("v_fma_mix_f32 %0, %1, %2, %0 op_sel:[1,0,0] op_sel_hi:[1,0,0]"     \
      : "+v"(acc)                                                         \
      : "v"(pk), "v"(v))

__device__ __forceinline__ int wave_iscan(int v, int lane) {
#pragma unroll
  for (int off = 1; off < 64; off <<= 1) {
    int t = __shfl_up(v, off, 64);
    if (lane >= off) v += t;
  }
  return v;
}

// Coarse multi-split, 512 threads: fused ego convert, then per-block LDS
// histogram + scan + reserve + reorder, bin-sorted copy-out to staging.
// Requires NC <= 1024 (n_nodes <= 262144).
__global__ __launch_bounds__(512) void k_part1(
    const int* __restrict__ rows, const int* __restrict__ cols,
    const float* __restrict__ vals, int* __restrict__ ccur,
    int2* __restrict__ cstag, int E,
    const float* __restrict__ ue, const float* __restrict__ ie,
    __half* __restrict__ h0, int nuser_e, int total_e) {
  __shared__ int cnt[1024];   // counts; after reserve, holds global bases
  __shared__ int offs[1024];
  __shared__ int lcur[1024];
  __shared__ int wsum8[8];
  __shared__ int2 sout[T1];
  __shared__ unsigned short sbin[T1];
  int tid = threadIdx.x;
  int lane = tid & 63, wid = tid >> 6;
  int base = blockIdx.x * T1;

  // fused ego init (streaming; overlaps other blocks' latency phases)
  for (int i = blockIdx.x * 512 + tid; i < total_e; i += gridDim.x * 512) {
    float x = (i < nuser_e) ? ue[i] : ie[i - nuser_e];
    h0[i] = __float2half(x);
  }

  cnt[tid] = 0;
  cnt[tid + 512] = 0;
  __syncthreads();

  int recx[EPT], recy[EPT], rbin[EPT];
#pragma unroll
  for (int k = 0; k < EPT; ++k) {
    int idx = base + k * 512 + tid;
    if (idx < E) {
      int r = rows[idx];
      int b = r >> CSH;
      recx[k] = cols[idx] | ((r & (CBROWS - 1)) << 18);
      recy[k] = __float_as_int(vals[idx]);
      rbin[k] = b;
      atomicAdd(&cnt[b], 1);
    } else {
      rbin[k] = -1;
    }
  }
  __syncthreads();

  // exclusive scan of 1024 counters: thread t owns slots 2t, 2t+1.
  int c0 = cnt[2 * tid], c1 = cnt[2 * tid + 1];
  int s = c0 + c1;
  int incl = wave_iscan(s, lane);
  if (lane == 63) wsum8[wid] = incl;
  __syncthreads();
  if (wid == 0) {
    int t = (lane < 8) ? wsum8[lane] : 0;
    t = wave_iscan(t, lane);
    if (lane < 8) wsum8[lane] = t;
  }
  __syncthreads();
  int woff = wid ? wsum8[wid - 1] : 0;
  incl += woff;
  int e0 = incl - s;
  offs[2 * tid] = e0;
  offs[2 * tid + 1] = e0 + c0;
  lcur[2 * tid] = e0;
  lcur[2 * tid + 1] = e0 + c0;
  __syncthreads();

  // reserve contiguous global ranges per bin; store base over cnt (each slot
  // read+written by the same thread -> no hazard).
#pragma unroll
  for (int j = 0; j < 2; ++j) {
    int t = tid + 512 * j;
    int c = cnt[t];
    if (c > 0) cnt[t] = atomicAdd(&ccur[t], c);
  }
  // bin-sorted reorder into LDS.
#pragma unroll
  for (int k = 0; k < EPT; ++k) {
    if (rbin[k] >= 0) {
      int p = atomicAdd(&lcur[rbin[k]], 1);
      sout[p] = make_int2(recx[k], recy[k]);
      sbin[p] = (unsigned short)rbin[k];
    }
  }
  __syncthreads();

  // run-coalesced copy-out: consecutive i -> same bin -> consecutive addrs.
  int m = min(T1, E - base);
  for (int i = tid; i < m; i += 512) {
    int b = sbin[i];
    int rel = cnt[b] + (i - offs[b]);  // cnt[] holds global base now
    if (rel < CAPC) cstag[(size_t)b * CAPC + rel] = sout[i];
  }
}

// Single-block exclusive scan of bin counts -> bin bases; also ptr[n]=E.
__global__ __launch_bounds__(1024) void k_binscan(
    const int* __restrict__ ccur, int* __restrict__ bbase,
    int* __restrict__ ptr, int nc, int n_nodes, int E) {
  __shared__ int wsum[16];
  int i = threadIdx.x;
  int lane = i & 63, wid = i >> 6;
  int v = (i < nc) ? min(ccur[i], CAPC) : 0;
  int incl = wave_iscan(v, lane);
  if (lane == 63) wsum[wid] = incl;
  __syncthreads();
  if (wid == 0) {
    int s = (lane < 16) ? wsum[lane] : 0;
    s = wave_iscan(s, lane);
    if (lane < 16) wsum[lane] = s;
  }
  __syncthreads();
  int woff = wid ? wsum[wid - 1] : 0;
  if (i < nc) bbase[i] = (incl + woff) - v;
  if (i == 0) ptr[n_nodes] = E;
}

// Fused CSR finalize: one block per bin. Stage records in LDS (int4 = 2
// records per load), per-row hist, in-block scan, scatter to final erec
// (bin's contiguous ~40KB chunk -> L2-resident), write ptr for bin's rows.
__global__ __launch_bounds__(512) void k_csr(
    const int2* __restrict__ cstag, const int* __restrict__ ccur,
    const int* __restrict__ bbase, int2* __restrict__ erec,
    int* __restrict__ ptr, int n_nodes) {
  __shared__ int2 srec[CAPC];     // 48KB
  __shared__ int hist[CBROWS];
  __shared__ int off[CBROWS];
  __shared__ int lcur[CBROWS];
  int b = blockIdx.x;
  int tid = threadIdx.x;
  int c = min(ccur[b], CAPC);
  int base = bbase[b];
  if (tid < CBROWS) hist[tid] = 0;
  __syncthreads();
  const int4* p4 = (const int4*)(cstag + (size_t)b * CAPC);
  for (int i = tid; 2 * i < c; i += 512) {
    int4 q = p4[i];
    srec[2 * i] = make_int2(q.x, q.y);
    atomicAdd(&hist[(q.x >> 18) & (CBROWS - 1)], 1);
    if (2 * i + 1 < c) {
      srec[2 * i + 1] = make_int2(q.z, q.w);
      atomicAdd(&hist[(q.z >> 18) & (CBROWS - 1)], 1);
    }
  }
  __syncthreads();
  // exclusive scan of 256 counters by wave 0 (lane l owns slots 4l..4l+3).
  if (tid < 64) {
    int h0 = hist[4 * tid], h1 = hist[4 * tid + 1];
    int h2 = hist[4 * tid + 2], h3 = hist[4 * tid + 3];
    int s = h0 + h1 + h2 + h3;
    int incl = wave_iscan(s, tid);
    int e0 = incl - s;
    off[4 * tid] = e0;
    off[4 * tid + 1] = e0 + h0;
    off[4 * tid + 2] = e0 + h0 + h1;
    off[4 * tid + 3] = e0 + h0 + h1 + h2;
  }
  __syncthreads();
  if (tid < CBROWS) lcur[tid] = off[tid];
  __syncthreads();
  for (int i = tid; i < c; i += 512) {
    int2 r = srec[i];
    int ro = (r.x >> 18) & (CBROWS - 1);
    int pos = atomicAdd(&lcur[ro], 1);
    erec[base + pos] = make_int2(r.x & COLMASK, r.y);
  }
  int row = (b << CSH) + tid;
  if (tid < CBROWS && row < n_nodes) ptr[row] = base + off[tid];
}

// Pull-SpMM: one wave per row; lane = slot(0..3) x chquad(0..15).
// 32 edges (8 per slot) in flight; phantom slots (past row end) have their
// gather offset masked to row 0 (L1-hot line) and value zeroed -- full MLP
// without phantom random-gather request traffic. v_fma_mix inner product.
// FIN: layer-3 sums stay fp32 in regs; epilogue fuses (h1+h2+h3)/3 and
// writes fp32 output directly. Blocks XCD-swizzled (bijective).
template <bool FIN>
__global__ __launch_bounds__(256) void k_spmm(
    const __half* __restrict__ cur, __half* __restrict__ nxt,
    const __half* __restrict__ h1, const __half* __restrict__ h2,
    float* __restrict__ out, const int* __restrict__ ptr,
    const int2* __restrict__ erec, int n, float scale) {
  // bijective XCD swizzle (m204 form): contiguous block ranges per XCD.
  int nwg = gridDim.x;
  int q = nwg >> 3, rr = nwg & 7;
  int xcd = blockIdx.x & 7, idx = blockIdx.x >> 3;
  int swz = (xcd < rr ? xcd * (q + 1) : rr * (q + 1) + (xcd - rr) * q) + idx;
  int w = (swz * 256 + threadIdx.x) >> 6;
  int lane = threadIdx.x & 63;
  if (w >= n) return;
  int start = ptr[w], end = ptr[w + 1];
  int sub = lane >> 4;
  int ch = (lane & 15) << 2;  // half-offset within the 64-wide row
  float a0 = 0.f, a1 = 0.f, a2 = 0.f, a3 = 0.f;
  float b0 = 0.f, b1 = 0.f, b2 = 0.f, b3 = 0.f;
  for (int j = start; j < end; j += 32) {
    int2 r[8];
#pragma unroll
    for (int k = 0; k < 8; ++k) r[k] = erec[j + sub + 4 * k];
    int off[8];
    float v[8];
#pragma unroll
    for (int k = 0; k < 8; ++k) {
      bool valid = j + sub + 4 * k < end;
      off[k] = valid ? (((r[k].x & COLMASK) << 6) + ch) : ch;
      v[k] = valid ? __int_as_float(r[k].y) : 0.f;
    }
    int2 g[8];
#pragma unroll
    for (int k = 0; k < 8; ++k) g[k] = *(const int2*)(cur + off[k]);
#pragma unroll
    for (int k = 0; k < 8; ++k) {
      if (k & 1) {
        FMAMIX_LO(b0, g[k].x, v[k]);
        FMAMIX_HI(b1, g[k].x, v[k]);
        FMAMIX_LO(b2, g[k].y, v[k]);
        FMAMIX_HI(b3, g[k].y, v[k]);
      } else {
        FMAMIX_LO(a0, g[k].x, v[k]);
        FMAMIX_HI(a1, g[k].x, v[k]);
        FMAMIX_LO(a2, g[k].y, v[k]);
        FMAMIX_HI(a3, g[k].y, v[k]);
      }
    }
  }
  a0 += b0; a1 += b1; a2 += b2; a3 += b3;
  a0 += __shfl_xor(a0, 16, 64); a0 += __shfl_xor(a0, 32, 64);
  a1 += __shfl_xor(a1, 16, 64); a1 += __shfl_xor(a1, 32, 64);
  a2 += __shfl_xor(a2, 16, 64); a2 += __shfl_xor(a2, 32, 64);
  a3 += __shfl_xor(a3, 16, 64); a3 += __shfl_xor(a3, 32, 64);
  if (sub == 0) {
    size_t o = ((size_t)w << 6) + ch;
    if (!FIN) {
      __half2 lo = __halves2half2(__float2half(a0), __float2half(a1));
      __half2 hi = __halves2half2(__float2half(a2), __float2half(a3));
      int2 pk;
      pk.x = *reinterpret_cast<int*>(&lo);
      pk.y = *reinterpret_cast<int*>(&hi);
      *reinterpret_cast<int2*>(nxt + o) = pk;
    } else {
      int2 x1 = *(const int2*)(h1 + o);
      int2 x2 = *(const int2*)(h2 + o);
      float2 u1a = __half22float2(*reinterpret_cast<__half2*>(&x1.x));
      float2 u1b = __half22float2(*reinterpret_cast<__half2*>(&x1.y));
      float2 u2a = __half22float2(*reinterpret_cast<__half2*>(&x2.x));
      float2 u2b = __half22float2(*reinterpret_cast<__half2*>(&x2.y));
      float4 r;
      r.x = (u1a.x + u2a.x + a0) * scale;
      r.y = (u1a.y + u2a.y + a1) * scale;
      r.z = (u1b.x + u2b.x + a2) * scale;
      r.w = (u1b.y + u2b.y + a3) * scale;
      *reinterpret_cast<float4*>(out + o) = r;
    }
  }
}

extern "C" void kernel_launch(void* const* d_in, const int* in_sizes, int n_in,
                              void* d_out, int out_size, void* d_ws,
                              size_t ws_size, hipStream_t stream) {
  const float* ue = (const float*)d_in[0];
  const float* ie = (const float*)d_in[1];
  const float* vals = (const float*)d_in[2];
  const int* rows = (const int*)d_in[3];
  const int* cols = (const int*)d_in[4];

  const int EMB = 64;
  const int n_users = in_sizes[0] / EMB;
  const int n_items = in_sizes[1] / EMB;
  const int n_nodes = n_users + n_items;
  const int E = in_sizes[2];
  const int total_e = n_nodes * EMB;
  const int NC = (n_nodes + CBROWS - 1) >> CSH;  // coarse bins (<=1024)

  // Workspace layout (~148 MB). NOTE: spmm record loads may read up to 31
  // records past erec[E-1]; those land inside cstag (allocated) and their
  // gathers/values are masked -- no OOB, no NaN.
  __half* h0 = (__half*)d_ws;           // ego
  __half* h1 = h0 + total_e;
  __half* h2 = h1 + total_e;
  int2* erec = (int2*)(h2 + total_e);   // final CSR records [E]
  int2* cstag = erec + E;               // coarse staging [NC*CAPC]
  int* ccur = (int*)(cstag + (size_t)NC * CAPC);  // coarse cursors [NC]
  int* bbase = ccur + NC + 8;           // bin bases [NC]
  int* ptr = bbase + NC + 8;            // CSR row_ptr [n_nodes+1]

  const int gP1 = (E + T1 - 1) / T1;
  const int gSpmm = (n_nodes + 3) / 4;

  // --- build ---
  hipMemsetAsync(ccur, 0, NC * sizeof(int), stream);
  k_part1<<<gP1, 512, 0, stream>>>(rows, cols, vals, ccur, cstag, E, ue, ie,
                                   h0, n_users * EMB, total_e);
  k_binscan<<<1, 1024, 0, stream>>>(ccur, bbase, ptr, NC, n_nodes, E);
  k_csr<<<NC, 512, 0, stream>>>(cstag, ccur, bbase, erec, ptr, n_nodes);

  // --- propagation; layer 3 fuses the mean + fp32 output write ---
  k_spmm<false><<<gSpmm, 256, 0, stream>>>(h0, h1, nullptr, nullptr, nullptr,
                                           ptr, erec, n_nodes, 0.f);
  k_spmm<false><<<gSpmm, 256, 0, stream>>>(h1, h2, nullptr, nullptr, nullptr,
                                           ptr, erec, n_nodes, 0.f);
  k_spmm<true><<<gSpmm, 256, 0, stream>>>(h2, nullptr, h1, h2, (float*)d_out,
                                          ptr, erec, n_nodes, 1.0f / 3.0f);
}

// Round 5
// 463.176 us; speedup vs baseline: 1.6313x; 1.1560x over previous
//
#include <hip/hip_runtime.h>
#include <hip/hip_fp16.h>

// DimCL encoder, R11.
//  - spmm gather restructured to 16B per lane-request: 8 lanes per edge row
//    (int4 = 8 halves each) instead of 16 lanes x 8B. Same cache-line
//    footprint, HALF the lane-address count -- attacks the per-lane
//    request-rate bound that R8/R9/R10's nulls isolated (64M -> 32M
//    lane-requests/layer; addr-path floor ~104us -> ~52us).
//  - per-row ranges stored as int2 (start,end): bin bases assigned by one
//    global atomicAdd inside k_csr (bin order in erec is arbitrary but
//    per-row segments stay contiguous). k_binscan deleted.
//  - build otherwise unchanged from R10.
// Layers fp16, all math fp32.

#define CSH 8             // 256 rows per coarse bin
#define CBROWS (1 << CSH)
#define CAPC 6144         // bin capacity (avg ~5120, ~14 sigma slack)
#define T1 4096           // edges per k_part1 block tile
#define EPT 8             // edges per thread in k_part1 (T1 = 512*EPT)
#define COLMASK 0x3FFFF   // n_nodes < 2^18

// acc += (float)lo_half(pk) * v   /   acc += (float)hi_half(pk) * v
#define FMAMIX_LO(acc, pk, v)                                             \
  asm("v_fma_mix_f32 %0, %1, %2, %0 op_sel:[0,0,0] op_sel_hi:[1,0,0]"     \
      : "+v"(acc)                                                         \
      : "v"(pk), "v"(v))
#define FMAMIX_HI(acc, pk, v)                                             \
  asm("v_fma_mix_f32 %0, %1, %2, %0 op_sel:[1,0,0] op_sel_hi:[1,0,0]"     \
      : "+v"(acc)                                                         \
      : "v"(pk), "v"(v))

__device__ __forceinline__ int wave_iscan(int v, int lane) {
#pragma unroll
  for (int off = 1; off < 64; off <<= 1) {
    int t = __shfl_up(v, off, 64);
    if (lane >= off) v += t;
  }
  return v;
}

// Coarse multi-split, 512 threads: fused ego convert, then per-block LDS
// histogram + scan + reserve + reorder, bin-sorted copy-out to staging.
// Requires NC <= 1024 (n_nodes <= 262144).
__global__ __launch_bounds__(512) void k_part1(
    const int* __restrict__ rows, const int* __restrict__ cols,
    const float* __restrict__ vals, int* __restrict__ ccur,
    int2* __restrict__ cstag, int E,
    const float* __restrict__ ue, const float* __restrict__ ie,
    __half* __restrict__ h0, int nuser_e, int total_e) {
  __shared__ int cnt[1024];   // counts; after reserve, holds global bases
  __shared__ int offs[1024];
  __shared__ int lcur[1024];
  __shared__ int wsum8[8];
  __shared__ int2 sout[T1];
  __shared__ unsigned short sbin[T1];
  int tid = threadIdx.x;
  int lane = tid & 63, wid = tid >> 6;
  int base = blockIdx.x * T1;

  // fused ego init (streaming; overlaps other blocks' latency phases)
  for (int i = blockIdx.x * 512 + tid; i < total_e; i += gridDim.x * 512) {
    float x = (i < nuser_e) ? ue[i] : ie[i - nuser_e];
    h0[i] = __float2half(x);
  }

  cnt[tid] = 0;
  cnt[tid + 512] = 0;
  __syncthreads();

  int recx[EPT], recy[EPT], rbin[EPT];
#pragma unroll
  for (int k = 0; k < EPT; ++k) {
    int idx = base + k * 512 + tid;
    if (idx < E) {
      int r = rows[idx];
      int b = r >> CSH;
      recx[k] = cols[idx] | ((r & (CBROWS - 1)) << 18);
      recy[k] = __float_as_int(vals[idx]);
      rbin[k] = b;
      atomicAdd(&cnt[b], 1);
    } else {
      rbin[k] = -1;
    }
  }
  __syncthreads();

  // exclusive scan of 1024 counters: thread t owns slots 2t, 2t+1.
  int c0 = cnt[2 * tid], c1 = cnt[2 * tid + 1];
  int s = c0 + c1;
  int incl = wave_iscan(s, lane);
  if (lane == 63) wsum8[wid] = incl;
  __syncthreads();
  if (wid == 0) {
    int t = (lane < 8) ? wsum8[lane] : 0;
    t = wave_iscan(t, lane);
    if (lane < 8) wsum8[lane] = t;
  }
  __syncthreads();
  int woff = wid ? wsum8[wid - 1] : 0;
  incl += woff;
  int e0 = incl - s;
  offs[2 * tid] = e0;
  offs[2 * tid + 1] = e0 + c0;
  lcur[2 * tid] = e0;
  lcur[2 * tid + 1] = e0 + c0;
  __syncthreads();

  // reserve contiguous global ranges per bin; store base over cnt (each slot
  // read+written by the same thread -> no hazard).
#pragma unroll
  for (int j = 0; j < 2; ++j) {
    int t = tid + 512 * j;
    int c = cnt[t];
    if (c > 0) cnt[t] = atomicAdd(&ccur[t], c);
  }
  // bin-sorted reorder into LDS.
#pragma unroll
  for (int k = 0; k < EPT; ++k) {
    if (rbin[k] >= 0) {
      int p = atomicAdd(&lcur[rbin[k]], 1);
      sout[p] = make_int2(recx[k], recy[k]);
      sbin[p] = (unsigned short)rbin[k];
    }
  }
  __syncthreads();

  // run-coalesced copy-out: consecutive i -> same bin -> consecutive addrs.
  int m = min(T1, E - base);
  for (int i = tid; i < m; i += 512) {
    int b = sbin[i];
    int rel = cnt[b] + (i - offs[b]);  // cnt[] holds global base now
    if (rel < CAPC) cstag[(size_t)b * CAPC + rel] = sout[i];
  }
}

// Fused CSR finalize: one block per bin. Bin base from a global atomic
// cursor (bin order in erec arbitrary; per-row segments contiguous).
// Stage records in LDS (int4 = 2 records per load), per-row hist, in-block
// scan, scatter to final erec (bin's contiguous ~40KB chunk, L2-resident),
// write per-row (start,end) int2.
__global__ __launch_bounds__(512) void k_csr(
    const int2* __restrict__ cstag, const int* __restrict__ ccur,
    int* __restrict__ gcur, int2* __restrict__ erec,
    int2* __restrict__ ptr2, int n_nodes) {
  __shared__ int2 srec[CAPC];     // 48KB
  __shared__ int hist[CBROWS];
  __shared__ int off[CBROWS];
  __shared__ int lcur[CBROWS];
  __shared__ int sbase;
  int b = blockIdx.x;
  int tid = threadIdx.x;
  int c = min(ccur[b], CAPC);
  if (tid < CBROWS) hist[tid] = 0;
  if (tid == 0) sbase = atomicAdd(gcur, c);
  __syncthreads();
  const int4* p4 = (const int4*)(cstag + (size_t)b * CAPC);
  for (int i = tid; 2 * i < c; i += 512) {
    int4 q = p4[i];
    srec[2 * i] = make_int2(q.x, q.y);
    atomicAdd(&hist[(q.x >> 18) & (CBROWS - 1)], 1);
    if (2 * i + 1 < c) {
      srec[2 * i + 1] = make_int2(q.z, q.w);
      atomicAdd(&hist[(q.z >> 18) & (CBROWS - 1)], 1);
    }
  }
  __syncthreads();
  // exclusive scan of 256 counters by wave 0 (lane l owns slots 4l..4l+3).
  if (tid < 64) {
    int h0 = hist[4 * tid], h1 = hist[4 * tid + 1];
    int h2 = hist[4 * tid + 2], h3 = hist[4 * tid + 3];
    int s = h0 + h1 + h2 + h3;
    int incl = wave_iscan(s, tid);
    int e0 = incl - s;
    off[4 * tid] = e0;
    off[4 * tid + 1] = e0 + h0;
    off[4 * tid + 2] = e0 + h0 + h1;
    off[4 * tid + 3] = e0 + h0 + h1 + h2;
  }
  __syncthreads();
  if (tid < CBROWS) lcur[tid] = off[tid];
  __syncthreads();
  int base = sbase;
  for (int i = tid; i < c; i += 512) {
    int2 r = srec[i];
    int ro = (r.x >> 18) & (CBROWS - 1);
    int pos = atomicAdd(&lcur[ro], 1);
    erec[base + pos] = make_int2(r.x & COLMASK, r.y);
  }
  int row = (b << CSH) + tid;
  if (tid < CBROWS && row < n_nodes) {
    int s0 = base + off[tid];
    ptr2[row] = make_int2(s0, s0 + hist[tid]);
  }
}

// Pull-SpMM: one wave per row; lane = slot(0..7) x choct(0..7).
// Each edge row (128B) gathered by 8 lanes x int4 (16B) -- half the
// lane-requests of the 16x8B form. 32 edges (4 per slot) in flight;
// phantom slots masked to row 0 (L1-hot) with zeroed value. v_fma_mix
// inner product, 8 fp32 accumulators, 3-level shfl_xor reduction.
// FIN: epilogue fuses (h1+h2+sum)/3, writes fp32 output directly.
// Blocks XCD-swizzled (bijective).
template <bool FIN>
__global__ __launch_bounds__(256) void k_spmm(
    const __half* __restrict__ cur, __half* __restrict__ nxt,
    const __half* __restrict__ h1, const __half* __restrict__ h2,
    float* __restrict__ out, const int2* __restrict__ ptr2,
    const int2* __restrict__ erec, int n, float scale) {
  // bijective XCD swizzle (m204 form): contiguous block ranges per XCD.
  int nwg = gridDim.x;
  int q = nwg >> 3, rr = nwg & 7;
  int xcd = blockIdx.x & 7, idx = blockIdx.x >> 3;
  int swz = (xcd < rr ? xcd * (q + 1) : rr * (q + 1) + (xcd - rr) * q) + idx;
  int w = (swz * 256 + threadIdx.x) >> 6;
  int lane = threadIdx.x & 63;
  if (w >= n) return;
  int2 se = ptr2[w];
  int start = se.x, end = se.y;
  int sub = lane >> 3;        // edge slot 0..7
  int ch = (lane & 7) << 3;   // half-offset within the 64-wide row (16B)
  float c0 = 0.f, c1 = 0.f, c2 = 0.f, c3 = 0.f;
  float c4 = 0.f, c5 = 0.f, c6 = 0.f, c7 = 0.f;
  for (int j = start; j < end; j += 32) {
    int2 r[4];
#pragma unroll
    for (int k = 0; k < 4; ++k) r[k] = erec[j + sub + 8 * k];
    int off[4];
    float v[4];
#pragma unroll
    for (int k = 0; k < 4; ++k) {
      bool valid = j + sub + 8 * k < end;
      off[k] = valid ? (((r[k].x & COLMASK) << 6) + ch) : ch;
      v[k] = valid ? __int_as_float(r[k].y) : 0.f;
    }
    int4 g[4];
#pragma unroll
    for (int k = 0; k < 4; ++k) g[k] = *(const int4*)(cur + off[k]);
#pragma unroll
    for (int k = 0; k < 4; ++k) {
      FMAMIX_LO(c0, g[k].x, v[k]);
      FMAMIX_HI(c1, g[k].x, v[k]);
      FMAMIX_LO(c2, g[k].y, v[k]);
      FMAMIX_HI(c3, g[k].y, v[k]);
      FMAMIX_LO(c4, g[k].z, v[k]);
      FMAMIX_HI(c5, g[k].z, v[k]);
      FMAMIX_LO(c6, g[k].w, v[k]);
      FMAMIX_HI(c7, g[k].w, v[k]);
    }
  }
  // reduce across the 8 slots (lanes with same ch, sub 0..7).
  c0 += __shfl_xor(c0, 8, 64); c0 += __shfl_xor(c0, 16, 64); c0 += __shfl_xor(c0, 32, 64);
  c1 += __shfl_xor(c1, 8, 64); c1 += __shfl_xor(c1, 16, 64); c1 += __shfl_xor(c1, 32, 64);
  c2 += __shfl_xor(c2, 8, 64); c2 += __shfl_xor(c2, 16, 64); c2 += __shfl_xor(c2, 32, 64);
  c3 += __shfl_xor(c3, 8, 64); c3 += __shfl_xor(c3, 16, 64); c3 += __shfl_xor(c3, 32, 64);
  c4 += __shfl_xor(c4, 8, 64); c4 += __shfl_xor(c4, 16, 64); c4 += __shfl_xor(c4, 32, 64);
  c5 += __shfl_xor(c5, 8, 64); c5 += __shfl_xor(c5, 16, 64); c5 += __shfl_xor(c5, 32, 64);
  c6 += __shfl_xor(c6, 8, 64); c6 += __shfl_xor(c6, 16, 64); c6 += __shfl_xor(c6, 32, 64);
  c7 += __shfl_xor(c7, 8, 64); c7 += __shfl_xor(c7, 16, 64); c7 += __shfl_xor(c7, 32, 64);
  if (sub == 0) {
    size_t o = ((size_t)w << 6) + ch;
    if (!FIN) {
      __half2 p0 = __halves2half2(__float2half(c0), __float2half(c1));
      __half2 p1 = __halves2half2(__float2half(c2), __float2half(c3));
      __half2 p2 = __halves2half2(__float2half(c4), __float2half(c5));
      __half2 p3 = __halves2half2(__float2half(c6), __float2half(c7));
      int4 pk;
      pk.x = *reinterpret_cast<int*>(&p0);
      pk.y = *reinterpret_cast<int*>(&p1);
      pk.z = *reinterpret_cast<int*>(&p2);
      pk.w = *reinterpret_cast<int*>(&p3);
      *reinterpret_cast<int4*>(nxt + o) = pk;
    } else {
      int4 x1 = *(const int4*)(h1 + o);
      int4 x2 = *(const int4*)(h2 + o);
      float2 u10 = __half22float2(*reinterpret_cast<__half2*>(&x1.x));
      float2 u11 = __half22float2(*reinterpret_cast<__half2*>(&x1.y));
      float2 u12 = __half22float2(*reinterpret_cast<__half2*>(&x1.z));
      float2 u13 = __half22float2(*reinterpret_cast<__half2*>(&x1.w));
      float2 u20 = __half22float2(*reinterpret_cast<__half2*>(&x2.x));
      float2 u21 = __half22float2(*reinterpret_cast<__half2*>(&x2.y));
      float2 u22 = __half22float2(*reinterpret_cast<__half2*>(&x2.z));
      float2 u23 = __half22float2(*reinterpret_cast<__half2*>(&x2.w));
      float4 r0, r1;
      r0.x = (u10.x + u20.x + c0) * scale;
      r0.y = (u10.y + u20.y + c1) * scale;
      r0.z = (u11.x + u21.x + c2) * scale;
      r0.w = (u11.y + u21.y + c3) * scale;
      r1.x = (u12.x + u22.x + c4) * scale;
      r1.y = (u12.y + u22.y + c5) * scale;
      r1.z = (u13.x + u23.x + c6) * scale;
      r1.w = (u13.y + u23.y + c7) * scale;
      *reinterpret_cast<float4*>(out + o) = r0;
      *reinterpret_cast<float4*>(out + o + 4) = r1;
    }
  }
}

extern "C" void kernel_launch(void* const* d_in, const int* in_sizes, int n_in,
                              void* d_out, int out_size, void* d_ws,
                              size_t ws_size, hipStream_t stream) {
  const float* ue = (const float*)d_in[0];
  const float* ie = (const float*)d_in[1];
  const float* vals = (const float*)d_in[2];
  const int* rows = (const int*)d_in[3];
  const int* cols = (const int*)d_in[4];

  const int EMB = 64;
  const int n_users = in_sizes[0] / EMB;
  const int n_items = in_sizes[1] / EMB;
  const int n_nodes = n_users + n_items;
  const int E = in_sizes[2];
  const int total_e = n_nodes * EMB;
  const int NC = (n_nodes + CBROWS - 1) >> CSH;  // coarse bins (<=1024)

  // Workspace layout (~148 MB). NOTE: spmm record loads may read up to 31
  // records past erec[E-1]; those land inside cstag (allocated) and their
  // gathers/values are masked -- no OOB, no NaN.
  __half* h0 = (__half*)d_ws;           // ego
  __half* h1 = h0 + total_e;
  __half* h2 = h1 + total_e;
  int2* erec = (int2*)(h2 + total_e);   // final CSR records [E]
  int2* cstag = erec + E;               // coarse staging [NC*CAPC]
  int* ccur = (int*)(cstag + (size_t)NC * CAPC);  // cursors [NC] + gcur [1]
  int* gcur = ccur + NC;
  int2* ptr2 = (int2*)(gcur + 8);       // per-row (start,end) [n_nodes]

  const int gP1 = (E + T1 - 1) / T1;
  const int gSpmm = (n_nodes + 3) / 4;

  // --- build ---
  hipMemsetAsync(ccur, 0, (NC + 1) * sizeof(int), stream);
  k_part1<<<gP1, 512, 0, stream>>>(rows, cols, vals, ccur, cstag, E, ue, ie,
                                   h0, n_users * EMB, total_e);
  k_csr<<<NC, 512, 0, stream>>>(cstag, ccur, gcur, erec, ptr2, n_nodes);

  // --- propagation; layer 3 fuses the mean + fp32 output write ---
  k_spmm<false><<<gSpmm, 256, 0, stream>>>(h0, h1, nullptr, nullptr, nullptr,
                                           ptr2, erec, n_nodes, 0.f);
  k_spmm<false><<<gSpmm, 256, 0, stream>>>(h1, h2, nullptr, nullptr, nullptr,
                                           ptr2, erec, n_nodes, 0.f);
  k_spmm<true><<<gSpmm, 256, 0, stream>>>(h2, nullptr, h1, h2, (float*)d_out,
                                          ptr2, erec, n_nodes, 1.0f / 3.0f);
}